// Round 1
// baseline (458.836 us; speedup 1.0000x reference)
//
#include <hip/hip_runtime.h>
#include <hip/hip_bf16.h>

typedef __attribute__((ext_vector_type(8))) short bf16x8;
typedef __attribute__((ext_vector_type(4))) float f32x4;

#define MFMA16(a, b, c) __builtin_amdgcn_mfma_f32_16x16x32_bf16((a), (b), (c), 0, 0, 0)

// ---------------------------------------------------------------------------
// Transpose + cast fp32 -> bf16:  in [R][C] (per z) -> out [C][R]
// ---------------------------------------------------------------------------
__global__ void transpose_cast(const float* __restrict__ in, __hip_bfloat16* __restrict__ out,
                               int R, int Ccols) {
    __shared__ float tile[32][33];
    int r0 = blockIdx.y * 32, c0 = blockIdx.x * 32;
    size_t zoff = (size_t)blockIdx.z * R * Ccols;
    const float* ib = in + zoff;
    __hip_bfloat16* ob = out + zoff;
    int tx = threadIdx.x, ty = threadIdx.y;
#pragma unroll
    for (int i = ty; i < 32; i += 8)
        tile[i][tx] = ib[(size_t)(r0 + i) * Ccols + c0 + tx];
    __syncthreads();
#pragma unroll
    for (int i = ty; i < 32; i += 8)
        ob[(size_t)(c0 + i) * R + r0 + tx] = __float2bfloat16(tile[tx][i]);
}

// rel_emb (63x256 fp32) -> bf16 padded to 64 rows (row 63 = 0)
__global__ void conv_rel(const float* __restrict__ rel, __hip_bfloat16* __restrict__ relb) {
    int i = blockIdx.x * 256 + threadIdx.x;  // 64*256 = 16384
    if (i < 64 * 256) {
        int r = i >> 8;
        relb[i] = __float2bfloat16(r < 63 ? rel[i] : 0.f);
    }
}

// ---------------------------------------------------------------------------
// Batched bf16 GEMM:  C[z] = A[z] (MxK, row-major) * B[z]^T (B stored [N][K]) + bias
// MODE 0: write bf16 row-major C[M][N]
// MODE 1: write fp32 to dout + z*16777216 at ((b*4096 + 2048 + n)*1024 + p), m=b*1024+p
// ---------------------------------------------------------------------------
struct GArgs {
    const __hip_bfloat16* A[6];
    const __hip_bfloat16* B[6];
    void* C[6];
    const float* bias[6];
};

template <int MODE>
__global__ __launch_bounds__(256, 2) void gemm_bt(GArgs ga, int M, int N, int K,
                                                  float* __restrict__ dout) {
    const int z = blockIdx.z;
    const __hip_bfloat16* __restrict__ A = ga.A[z];
    const __hip_bfloat16* __restrict__ Bt = ga.B[z];
    const float* __restrict__ bias = ga.bias[z];

    __shared__ __align__(16) __hip_bfloat16 As[128 * 32];
    __shared__ __align__(16) __hip_bfloat16 Bs[128 * 32];

    const int tid = threadIdx.x;
    const int wave = tid >> 6, lane = tid & 63;
    const int l15 = lane & 15, lg = lane >> 4;
    const int wm = wave >> 1, wn = wave & 1;
    const size_t row0 = (size_t)blockIdx.y * 128;
    const size_t col0 = (size_t)blockIdx.x * 128;

    f32x4 acc[4][4] = {};

    const int sm0 = tid >> 2;           // 0..63
    const int sk0 = (tid & 3) * 8;      // 0,8,16,24

    for (int k0 = 0; k0 < K; k0 += 32) {
        bf16x8 a0 = *(const bf16x8*)&A[(row0 + sm0) * K + k0 + sk0];
        bf16x8 a1 = *(const bf16x8*)&A[(row0 + 64 + sm0) * K + k0 + sk0];
        bf16x8 b0 = *(const bf16x8*)&Bt[(col0 + sm0) * K + k0 + sk0];
        bf16x8 b1 = *(const bf16x8*)&Bt[(col0 + 64 + sm0) * K + k0 + sk0];
        __syncthreads();  // previous iter's LDS reads done
        *(bf16x8*)&As[sm0 * 32 + sk0] = a0;
        *(bf16x8*)&As[(64 + sm0) * 32 + sk0] = a1;
        *(bf16x8*)&Bs[sm0 * 32 + sk0] = b0;
        *(bf16x8*)&Bs[(64 + sm0) * 32 + sk0] = b1;
        __syncthreads();
        bf16x8 af[4], bfr[4];
#pragma unroll
        for (int i = 0; i < 4; ++i) {
            af[i] = *(const bf16x8*)&As[(wm * 64 + i * 16 + l15) * 32 + lg * 8];
            bfr[i] = *(const bf16x8*)&Bs[(wn * 64 + i * 16 + l15) * 32 + lg * 8];
        }
#pragma unroll
        for (int i = 0; i < 4; ++i)
#pragma unroll
            for (int j = 0; j < 4; ++j)
                acc[i][j] = MFMA16(af[i], bfr[j], acc[i][j]);
    }

    if (MODE == 0) {
        __hip_bfloat16* __restrict__ C = (__hip_bfloat16*)ga.C[z];
#pragma unroll
        for (int i = 0; i < 4; ++i) {
            size_t mb = row0 + wm * 64 + i * 16 + lg * 4;
#pragma unroll
            for (int j = 0; j < 4; ++j) {
                int n = (int)col0 + wn * 64 + j * 16 + l15;
                float bv = bias[n];
#pragma unroll
                for (int r = 0; r < 4; ++r)
                    C[(mb + r) * N + n] = __float2bfloat16(acc[i][j][r] + bv);
            }
        }
    } else {
        float* __restrict__ OB = dout + (size_t)z * 16777216;
#pragma unroll
        for (int i = 0; i < 4; ++i) {
            size_t mb = row0 + wm * 64 + i * 16 + lg * 4;
#pragma unroll
            for (int j = 0; j < 4; ++j) {
                int n = (int)col0 + wn * 64 + j * 16 + l15;
                float bv = bias[n];
#pragma unroll
                for (int r = 0; r < 4; ++r) {
                    size_t m = mb + r;
                    size_t bb = m >> 10, p = m & 1023;
                    OB[(bb * 4096 + 2048 + (size_t)n) * 1024 + p] = acc[i][j][r] + bv;
                }
            }
        }
    }
}

// ---------------------------------------------------------------------------
// Axial attention: one block per (dir, b, head, w).  Q,K,V row-major [4096][2048] bf16.
// scores[h][k] = (q_h . k_k + E[h][(k-h)%63] + E[h][(k-w)%63]) / 16, softmax over k,
// att = P @ V  -> O row-major bf16.
// ---------------------------------------------------------------------------
__global__ __launch_bounds__(256, 2) void attn_kernel(
    const __hip_bfloat16* __restrict__ Qa, const __hip_bfloat16* __restrict__ Ka,
    const __hip_bfloat16* __restrict__ Va, const __hip_bfloat16* __restrict__ Qb,
    const __hip_bfloat16* __restrict__ Kb, const __hip_bfloat16* __restrict__ Vb,
    const __hip_bfloat16* __restrict__ relb, __hip_bfloat16* __restrict__ Oa,
    __hip_bfloat16* __restrict__ Ob) {
    const int w = blockIdx.x;   // 0..31
    const int nh = blockIdx.y;  // 0..7
    const int zb = blockIdx.z;  // dir*4 + b
    const int dir = zb >> 2, b = zb & 3;
    const __hip_bfloat16* __restrict__ Q = dir ? Qb : Qa;
    const __hip_bfloat16* __restrict__ K = dir ? Kb : Ka;
    const __hip_bfloat16* __restrict__ V = dir ? Vb : Va;
    __hip_bfloat16* __restrict__ O = dir ? Ob : Oa;

    __shared__ __align__(16) __hip_bfloat16 vt[256 * 40];  // V^T, stride 40 (80B, 16B-aligned)
    __shared__ float ssc[32 * 32];
    __shared__ float es[32 * 64];
    __shared__ __align__(16) __hip_bfloat16 ps[32 * 32];

    const int tid = threadIdx.x;
    const int lane = tid & 63, wave = tid >> 6;
    const int l15 = lane & 15, lg = lane >> 4;
    const int mt = wave >> 1, nt = wave & 1;

    const size_t rowbase = ((size_t)b * 1024 + w) * 2048 + (size_t)nh * 256;

    // stage V transposed: vt[c][hk]
    for (int i = 0; i < 32; ++i) {
        int e = i * 256 + tid;
        int hk = e >> 8, c = e & 255;
        vt[c * 40 + hk] = V[rowbase + (size_t)hk * 65536 + c];
    }

    // S (32x32) and E (32x64) via MFMA, fragments straight from global (L2-resident)
    f32x4 sacc = {}, e0 = {}, e1 = {};
#pragma unroll
    for (int k8 = 0; k8 < 256; k8 += 32) {
        bf16x8 af = *(const bf16x8*)&Q[rowbase + (size_t)(mt * 16 + l15) * 65536 + k8 + lg * 8];
        bf16x8 bf = *(const bf16x8*)&K[rowbase + (size_t)(nt * 16 + l15) * 65536 + k8 + lg * 8];
        bf16x8 r0 = *(const bf16x8*)&relb[(size_t)(nt * 32 + l15) * 256 + k8 + lg * 8];
        bf16x8 r1 = *(const bf16x8*)&relb[(size_t)(nt * 32 + 16 + l15) * 256 + k8 + lg * 8];
        sacc = MFMA16(af, bf, sacc);
        e0 = MFMA16(af, r0, e0);
        e1 = MFMA16(af, r1, e1);
    }
#pragma unroll
    for (int r = 0; r < 4; ++r) {
        int row = mt * 16 + lg * 4 + r;
        ssc[row * 32 + nt * 16 + l15] = sacc[r];
        es[row * 64 + nt * 32 + l15] = e0[r];
        es[row * 64 + nt * 32 + 16 + l15] = e1[r];
    }
    __syncthreads();

    // softmax: 8 threads per row, 4 cols each
    {
        int h = tid >> 3, sub = tid & 7;
        float v4[4];
        float mx = -1e30f;
#pragma unroll
        for (int i = 0; i < 4; ++i) {
            int k = sub * 4 + i;
            int dh = k - h; if (dh < 0) dh += 63;
            int dw = k - w; if (dw < 0) dw += 63;
            float s = (ssc[h * 32 + k] + es[h * 64 + dh] + es[h * 64 + dw]) * 0.0625f;
            v4[i] = s;
            mx = fmaxf(mx, s);
        }
        mx = fmaxf(mx, __shfl_xor(mx, 1));
        mx = fmaxf(mx, __shfl_xor(mx, 2));
        mx = fmaxf(mx, __shfl_xor(mx, 4));
        float sum = 0.f;
#pragma unroll
        for (int i = 0; i < 4; ++i) {
            v4[i] = __expf(v4[i] - mx);
            sum += v4[i];
        }
        sum += __shfl_xor(sum, 1);
        sum += __shfl_xor(sum, 2);
        sum += __shfl_xor(sum, 4);
        float inv = 1.f / sum;
#pragma unroll
        for (int i = 0; i < 4; ++i) ps[h * 32 + sub * 4 + i] = __float2bfloat16(v4[i] * inv);
    }
    __syncthreads();

    // att = P @ V : wave -> m-tile mt, 8 c-tiles starting at nt*8
    bf16x8 paf = *(const bf16x8*)&ps[(mt * 16 + l15) * 32 + lg * 8];
#pragma unroll
    for (int j = 0; j < 8; ++j) {
        int ct = nt * 8 + j;  // 0..15
        bf16x8 bv = *(const bf16x8*)&vt[(size_t)(ct * 16 + l15) * 40 + lg * 8];
        f32x4 oacc = {};
        oacc = MFMA16(paf, bv, oacc);
#pragma unroll
        for (int r = 0; r < 4; ++r) {
            int hh = mt * 16 + lg * 4 + r;
            O[rowbase + (size_t)hh * 65536 + ct * 16 + l15] = __float2bfloat16(oacc[r]);
        }
    }
}

// ---------------------------------------------------------------------------
// Copy raw features into first 2048 channels of each output tensor
// ---------------------------------------------------------------------------
__global__ void copy_feats(const float4* __restrict__ L, const float4* __restrict__ R,
                           float4* __restrict__ out) {
    int idx = blockIdx.x * 256 + threadIdx.x;  // 0 .. 2*2097152-1
    int t = idx >= 2097152;
    int f4 = t ? idx - 2097152 : idx;
    int b = f4 >> 19, rem = f4 & 524287;  // per-batch 2^19 float4
    float4 v = t ? R[f4] : L[f4];
    out[(size_t)t * 4194304 + (size_t)b * 1048576 + rem] = v;
}

// ---------------------------------------------------------------------------
extern "C" void kernel_launch(void* const* d_in, const int* in_sizes, int n_in, void* d_out,
                              int out_size, void* d_ws, size_t ws_size, hipStream_t stream) {
    const float* Xl = (const float*)d_in[0];
    const float* Xr = (const float*)d_in[1];
    const float* Wq = (const float*)d_in[2];
    const float* bq = (const float*)d_in[3];
    const float* Wk = (const float*)d_in[4];
    const float* bk = (const float*)d_in[5];
    const float* Wv = (const float*)d_in[6];
    const float* bv = (const float*)d_in[7];
    const float* Wo = (const float*)d_in[8];
    const float* bo = (const float*)d_in[9];
    const float* rel = (const float*)d_in[10];
    float* out = (float*)d_out;

    char* ws = (char*)d_ws;
    size_t off = 0;
    auto nxt = [&](size_t bytes) {
        void* p = ws + off;
        off += bytes;
        return p;
    };
    __hip_bfloat16* Xbl = (__hip_bfloat16*)nxt(16777216);
    __hip_bfloat16* Xbr = (__hip_bfloat16*)nxt(16777216);
    __hip_bfloat16* Wtq = (__hip_bfloat16*)nxt(8388608);
    __hip_bfloat16* Wtk = (__hip_bfloat16*)nxt(8388608);
    __hip_bfloat16* Wtv = (__hip_bfloat16*)nxt(8388608);
    __hip_bfloat16* Wto = (__hip_bfloat16*)nxt(8388608);
    __hip_bfloat16* relb = (__hip_bfloat16*)nxt(32768);
    __hip_bfloat16* Ql = (__hip_bfloat16*)nxt(16777216);
    __hip_bfloat16* Kl = (__hip_bfloat16*)nxt(16777216);
    __hip_bfloat16* Vl = (__hip_bfloat16*)nxt(16777216);
    __hip_bfloat16* Qr = (__hip_bfloat16*)nxt(16777216);
    __hip_bfloat16* Kr = (__hip_bfloat16*)nxt(16777216);
    __hip_bfloat16* Vr = (__hip_bfloat16*)nxt(16777216);
    // att outputs alias the Xb buffers (Xb dead after phase-1 GEMM)
    __hip_bfloat16* At0 = Xbl;
    __hip_bfloat16* At1 = Xbr;

    dim3 tb(32, 8);
    // X: (b, c=2048, p=1024) -> (b, p, c) bf16
    transpose_cast<<<dim3(32, 64, 4), tb, 0, stream>>>(Xl, Xbl, 2048, 1024);
    transpose_cast<<<dim3(32, 64, 4), tb, 0, stream>>>(Xr, Xbr, 2048, 1024);
    // W: [K=2048][N=2048] -> [N][K] bf16
    transpose_cast<<<dim3(64, 64, 1), tb, 0, stream>>>(Wq, Wtq, 2048, 2048);
    transpose_cast<<<dim3(64, 64, 1), tb, 0, stream>>>(Wk, Wtk, 2048, 2048);
    transpose_cast<<<dim3(64, 64, 1), tb, 0, stream>>>(Wv, Wtv, 2048, 2048);
    transpose_cast<<<dim3(64, 64, 1), tb, 0, stream>>>(Wo, Wto, 2048, 2048);
    conv_rel<<<64, 256, 0, stream>>>(rel, relb);

    GArgs g1 = {};
    g1.A[0] = Xbl; g1.A[1] = Xbl; g1.A[2] = Xbl;
    g1.A[3] = Xbr; g1.A[4] = Xbr; g1.A[5] = Xbr;
    g1.B[0] = Wtq; g1.B[1] = Wtk; g1.B[2] = Wtv;
    g1.B[3] = Wtq; g1.B[4] = Wtk; g1.B[5] = Wtv;
    g1.C[0] = Ql; g1.C[1] = Kl; g1.C[2] = Vl;
    g1.C[3] = Qr; g1.C[4] = Kr; g1.C[5] = Vr;
    g1.bias[0] = bq; g1.bias[1] = bk; g1.bias[2] = bv;
    g1.bias[3] = bq; g1.bias[4] = bk; g1.bias[5] = bv;
    gemm_bt<0><<<dim3(16, 32, 6), 256, 0, stream>>>(g1, 4096, 2048, 2048, nullptr);

    // dir0: weighted_r = attn(Q_l, K_r, V_r); dir1: weighted_l = attn(Q_r, K_l, V_l)
    attn_kernel<<<dim3(32, 8, 8), 256, 0, stream>>>(Ql, Kr, Vr, Qr, Kl, Vl, relb, At0, At1);

    GArgs g2 = {};
    g2.A[0] = At0; g2.A[1] = At1;
    g2.B[0] = Wto; g2.B[1] = Wto;
    g2.bias[0] = bo; g2.bias[1] = bo;
    gemm_bt<1><<<dim3(16, 32, 2), 256, 0, stream>>>(g2, 4096, 2048, 2048, out);

    copy_feats<<<16384, 256, 0, stream>>>((const float4*)Xl, (const float4*)Xr, (float4*)out);
}

// Round 2
// 443.038 us; speedup vs baseline: 1.0357x; 1.0357x over previous
//
#include <hip/hip_runtime.h>
#include <hip/hip_bf16.h>

typedef __attribute__((ext_vector_type(8))) short bf16x8;
typedef __attribute__((ext_vector_type(4))) float f32x4;

#define MFMA16(a, b, c) __builtin_amdgcn_mfma_f32_16x16x32_bf16((a), (b), (c), 0, 0, 0)

typedef __attribute__((address_space(1))) const void gconst_t;
typedef __attribute__((address_space(3))) void lds_t;
__device__ __forceinline__ void gload16(const void* gp, void* lp) {
    __builtin_amdgcn_global_load_lds((gconst_t*)gp, (lds_t*)lp, 16, 0, 0);
}

// ---------------------------------------------------------------------------
// Transpose + cast fp32 -> bf16:  in [R][C] (per z) -> out [C][R]
// ---------------------------------------------------------------------------
__global__ void transpose_cast(const float* __restrict__ in, __hip_bfloat16* __restrict__ out,
                               int R, int Ccols) {
    __shared__ float tile[32][33];
    int r0 = blockIdx.y * 32, c0 = blockIdx.x * 32;
    size_t zoff = (size_t)blockIdx.z * R * Ccols;
    const float* ib = in + zoff;
    __hip_bfloat16* ob = out + zoff;
    int tx = threadIdx.x, ty = threadIdx.y;
#pragma unroll
    for (int i = ty; i < 32; i += 8)
        tile[i][tx] = ib[(size_t)(r0 + i) * Ccols + c0 + tx];
    __syncthreads();
#pragma unroll
    for (int i = ty; i < 32; i += 8)
        ob[(size_t)(c0 + i) * R + r0 + tx] = __float2bfloat16(tile[tx][i]);
}

// rel_emb (63x256 fp32) -> bf16 padded to 64 rows (row 63 = 0)
__global__ void conv_rel(const float* __restrict__ rel, __hip_bfloat16* __restrict__ relb) {
    int i = blockIdx.x * 256 + threadIdx.x;  // 64*256 = 16384
    if (i < 64 * 256) {
        int r = i >> 8;
        relb[i] = __float2bfloat16(r < 63 ? rel[i] : 0.f);
    }
}

// ---------------------------------------------------------------------------
// Batched bf16 GEMM:  C[z] = A[z] (MxK, row-major) * B[z]^T (B stored [N][K]) + bias
// Staging via global_load_lds width=16 (linear LDS: byte tid*16 per K-tile half).
// MODE 0: write bf16 row-major C[M][N], bias[col]
// MODE 1: operands pre-swapped at launch (A=Wo^T rows=outchannel, B=att rows=m).
//         acc[row=n][col=m]; write fp32 to dout + z*16777216 at
//         ((m>>10)*4096 + 2048 + n)*1024 + (m&1023); bias[row]. Coalesced in m.
// ---------------------------------------------------------------------------
struct GArgs {
    const __hip_bfloat16* A[6];
    const __hip_bfloat16* B[6];
    void* C[6];
    const float* bias[6];
};

template <int MODE>
__global__ __launch_bounds__(256, 2) void gemm_bt(GArgs ga, int N, int K,
                                                  float* __restrict__ dout) {
    // XCD-aware chunked swizzle (nwg % 8 == 0 for all our launches)
    const int gx = gridDim.x, gy = gridDim.y;
    int lid = blockIdx.x + gx * (blockIdx.y + gy * blockIdx.z);
    const int nwg = gx * gy * gridDim.z;
    int swz = (lid & 7) * (nwg >> 3) + (lid >> 3);
    const int z = swz / (gx * gy);
    int rem = swz - z * gx * gy;
    const int by = rem / gx;
    const int bx = rem - by * gx;

    const __hip_bfloat16* __restrict__ A = ga.A[z];
    const __hip_bfloat16* __restrict__ Bt = ga.B[z];
    const float* __restrict__ bias = ga.bias[z];

    __shared__ __align__(16) __hip_bfloat16 As[128 * 32];
    __shared__ __align__(16) __hip_bfloat16 Bs[128 * 32];

    const int tid = threadIdx.x;
    const int wave = tid >> 6, lane = tid & 63;
    const int l15 = lane & 15, lg = lane >> 4;
    const int wm = wave >> 1, wn = wave & 1;
    const size_t row0 = (size_t)by * 128;
    const size_t col0 = (size_t)bx * 128;

    f32x4 acc[4][4] = {};

    // staging addresses: thread tid loads 16B of row (tid>>2), chunk (tid&3),
    // landing at LDS byte tid*16 (wave-uniform base + lane*16 — gload_lds layout)
    const int sm = tid >> 2;        // 0..63 row within 64-row half
    const int sk = (tid & 3) * 8;   // elem col
    const __hip_bfloat16* Ap = A + (row0 + sm) * K + sk;
    const __hip_bfloat16* Bp = Bt + (col0 + sm) * K + sk;
    char* AsW = (char*)As + wave * 1024;
    char* BsW = (char*)Bs + wave * 1024;

    for (int k0 = 0; k0 < K; k0 += 32) {
        __syncthreads();  // previous iter's LDS reads done
        gload16(Ap + k0, AsW);
        gload16(Ap + (size_t)64 * K + k0, AsW + 4096);
        gload16(Bp + k0, BsW);
        gload16(Bp + (size_t)64 * K + k0, BsW + 4096);
        __syncthreads();  // drains vmcnt(0) -> staged data visible
        bf16x8 af[4], bfr[4];
#pragma unroll
        for (int i = 0; i < 4; ++i) {
            af[i] = *(const bf16x8*)&As[(wm * 64 + i * 16 + l15) * 32 + lg * 8];
            bfr[i] = *(const bf16x8*)&Bs[(wn * 64 + i * 16 + l15) * 32 + lg * 8];
        }
#pragma unroll
        for (int i = 0; i < 4; ++i)
#pragma unroll
            for (int j = 0; j < 4; ++j)
                acc[i][j] = MFMA16(af[i], bfr[j], acc[i][j]);
    }

    if (MODE == 0) {
        __hip_bfloat16* __restrict__ C = (__hip_bfloat16*)ga.C[z];
#pragma unroll
        for (int i = 0; i < 4; ++i) {
            size_t mb = row0 + wm * 64 + i * 16 + lg * 4;
#pragma unroll
            for (int j = 0; j < 4; ++j) {
                int n = (int)col0 + wn * 64 + j * 16 + l15;
                float bv = bias[n];
#pragma unroll
                for (int r = 0; r < 4; ++r)
                    C[(mb + r) * N + n] = __float2bfloat16(acc[i][j][r] + bv);
            }
        }
    } else {
        // rows = output channel n, cols = m = b*1024 + p  (coalesced stores in p)
        float* __restrict__ OB = dout + (size_t)z * 16777216;
#pragma unroll
        for (int i = 0; i < 4; ++i) {
            size_t nb = row0 + wm * 64 + i * 16 + lg * 4;
#pragma unroll
            for (int j = 0; j < 4; ++j) {
                int m = (int)col0 + wn * 64 + j * 16 + l15;
                size_t base = (size_t)(m >> 10) * 4194304 + (size_t)(m & 1023);
#pragma unroll
                for (int r = 0; r < 4; ++r) {
                    size_t n = nb + r;
                    OB[base + (2048 + n) * 1024] = acc[i][j][r] + bias[n];
                }
            }
        }
    }
}

// ---------------------------------------------------------------------------
// Axial attention: one block per (dir, b, head, w).  Q,K,V row-major [4096][2048] bf16.
// scores[h][k] = (q_h . k_k + E[h][(k-h)%63] + E[h][(k-w)%63]) / 16, softmax over k,
// att = P @ V  -> O row-major bf16.
// ---------------------------------------------------------------------------
__global__ __launch_bounds__(256, 2) void attn_kernel(
    const __hip_bfloat16* __restrict__ Qa, const __hip_bfloat16* __restrict__ Ka,
    const __hip_bfloat16* __restrict__ Va, const __hip_bfloat16* __restrict__ Qb,
    const __hip_bfloat16* __restrict__ Kb, const __hip_bfloat16* __restrict__ Vb,
    const __hip_bfloat16* __restrict__ relb, __hip_bfloat16* __restrict__ Oa,
    __hip_bfloat16* __restrict__ Ob) {
    const int w = blockIdx.x;   // 0..31
    const int nh = blockIdx.y;  // 0..7
    const int zb = blockIdx.z;  // dir*4 + b
    const int dir = zb >> 2, b = zb & 3;
    const __hip_bfloat16* __restrict__ Q = dir ? Qb : Qa;
    const __hip_bfloat16* __restrict__ K = dir ? Kb : Ka;
    const __hip_bfloat16* __restrict__ V = dir ? Vb : Va;
    __hip_bfloat16* __restrict__ O = dir ? Ob : Oa;

    __shared__ __align__(16) __hip_bfloat16 vt[256 * 40];  // V^T, stride 40 (80B, 16B-aligned)
    __shared__ float ssc[32 * 32];
    __shared__ float es[32 * 64];
    __shared__ __align__(16) __hip_bfloat16 ps[32 * 32];

    const int tid = threadIdx.x;
    const int lane = tid & 63, wave = tid >> 6;
    const int l15 = lane & 15, lg = lane >> 4;
    const int mt = wave >> 1, nt = wave & 1;

    const size_t rowbase = ((size_t)b * 1024 + w) * 2048 + (size_t)nh * 256;

    // stage V transposed: vt[c][hk]
    for (int i = 0; i < 32; ++i) {
        int e = i * 256 + tid;
        int hk = e >> 8, c = e & 255;
        vt[c * 40 + hk] = V[rowbase + (size_t)hk * 65536 + c];
    }

    // S (32x32) and E (32x64) via MFMA, fragments straight from global (L2-resident)
    f32x4 sacc = {}, e0 = {}, e1 = {};
#pragma unroll
    for (int k8 = 0; k8 < 256; k8 += 32) {
        bf16x8 af = *(const bf16x8*)&Q[rowbase + (size_t)(mt * 16 + l15) * 65536 + k8 + lg * 8];
        bf16x8 bf = *(const bf16x8*)&K[rowbase + (size_t)(nt * 16 + l15) * 65536 + k8 + lg * 8];
        bf16x8 r0 = *(const bf16x8*)&relb[(size_t)(nt * 32 + l15) * 256 + k8 + lg * 8];
        bf16x8 r1 = *(const bf16x8*)&relb[(size_t)(nt * 32 + 16 + l15) * 256 + k8 + lg * 8];
        sacc = MFMA16(af, bf, sacc);
        e0 = MFMA16(af, r0, e0);
        e1 = MFMA16(af, r1, e1);
    }
#pragma unroll
    for (int r = 0; r < 4; ++r) {
        int row = mt * 16 + lg * 4 + r;
        ssc[row * 32 + nt * 16 + l15] = sacc[r];
        es[row * 64 + nt * 32 + l15] = e0[r];
        es[row * 64 + nt * 32 + 16 + l15] = e1[r];
    }
    __syncthreads();

    // softmax: 8 threads per row, 4 cols each
    {
        int h = tid >> 3, sub = tid & 7;
        float v4[4];
        float mx = -1e30f;
#pragma unroll
        for (int i = 0; i < 4; ++i) {
            int k = sub * 4 + i;
            int dh = k - h; if (dh < 0) dh += 63;
            int dw = k - w; if (dw < 0) dw += 63;
            float s = (ssc[h * 32 + k] + es[h * 64 + dh] + es[h * 64 + dw]) * 0.0625f;
            v4[i] = s;
            mx = fmaxf(mx, s);
        }
        mx = fmaxf(mx, __shfl_xor(mx, 1));
        mx = fmaxf(mx, __shfl_xor(mx, 2));
        mx = fmaxf(mx, __shfl_xor(mx, 4));
        float sum = 0.f;
#pragma unroll
        for (int i = 0; i < 4; ++i) {
            v4[i] = __expf(v4[i] - mx);
            sum += v4[i];
        }
        sum += __shfl_xor(sum, 1);
        sum += __shfl_xor(sum, 2);
        sum += __shfl_xor(sum, 4);
        float inv = 1.f / sum;
#pragma unroll
        for (int i = 0; i < 4; ++i) ps[h * 32 + sub * 4 + i] = __float2bfloat16(v4[i] * inv);
    }
    __syncthreads();

    // att = P @ V : wave -> m-tile mt, 8 c-tiles starting at nt*8
    bf16x8 paf = *(const bf16x8*)&ps[(mt * 16 + l15) * 32 + lg * 8];
#pragma unroll
    for (int j = 0; j < 8; ++j) {
        int ct = nt * 8 + j;  // 0..15
        bf16x8 bv = *(const bf16x8*)&vt[(size_t)(ct * 16 + l15) * 40 + lg * 8];
        f32x4 oacc = {};
        oacc = MFMA16(paf, bv, oacc);
#pragma unroll
        for (int r = 0; r < 4; ++r) {
            int hh = mt * 16 + lg * 4 + r;
            O[rowbase + (size_t)hh * 65536 + ct * 16 + l15] = __float2bfloat16(oacc[r]);
        }
    }
}

// ---------------------------------------------------------------------------
// Copy raw features into first 2048 channels of each output tensor
// ---------------------------------------------------------------------------
__global__ void copy_feats(const float4* __restrict__ L, const float4* __restrict__ R,
                           float4* __restrict__ out) {
    int idx = blockIdx.x * 256 + threadIdx.x;  // 0 .. 2*2097152-1
    int t = idx >= 2097152;
    int f4 = t ? idx - 2097152 : idx;
    int b = f4 >> 19, rem = f4 & 524287;  // per-batch 2^19 float4
    float4 v = t ? R[f4] : L[f4];
    out[(size_t)t * 4194304 + (size_t)b * 1048576 + rem] = v;
}

// ---------------------------------------------------------------------------
extern "C" void kernel_launch(void* const* d_in, const int* in_sizes, int n_in, void* d_out,
                              int out_size, void* d_ws, size_t ws_size, hipStream_t stream) {
    const float* Xl = (const float*)d_in[0];
    const float* Xr = (const float*)d_in[1];
    const float* Wq = (const float*)d_in[2];
    const float* bq = (const float*)d_in[3];
    const float* Wk = (const float*)d_in[4];
    const float* bk = (const float*)d_in[5];
    const float* Wv = (const float*)d_in[6];
    const float* bv = (const float*)d_in[7];
    const float* Wo = (const float*)d_in[8];
    const float* bo = (const float*)d_in[9];
    const float* rel = (const float*)d_in[10];
    float* out = (float*)d_out;

    char* ws = (char*)d_ws;
    size_t off = 0;
    auto nxt = [&](size_t bytes) {
        void* p = ws + off;
        off += bytes;
        return p;
    };
    __hip_bfloat16* Xbl = (__hip_bfloat16*)nxt(16777216);
    __hip_bfloat16* Xbr = (__hip_bfloat16*)nxt(16777216);
    __hip_bfloat16* Wtq = (__hip_bfloat16*)nxt(8388608);
    __hip_bfloat16* Wtk = (__hip_bfloat16*)nxt(8388608);
    __hip_bfloat16* Wtv = (__hip_bfloat16*)nxt(8388608);
    __hip_bfloat16* Wto = (__hip_bfloat16*)nxt(8388608);
    __hip_bfloat16* relb = (__hip_bfloat16*)nxt(32768);
    __hip_bfloat16* Ql = (__hip_bfloat16*)nxt(16777216);
    __hip_bfloat16* Kl = (__hip_bfloat16*)nxt(16777216);
    __hip_bfloat16* Vl = (__hip_bfloat16*)nxt(16777216);
    __hip_bfloat16* Qr = (__hip_bfloat16*)nxt(16777216);
    __hip_bfloat16* Kr = (__hip_bfloat16*)nxt(16777216);
    __hip_bfloat16* Vr = (__hip_bfloat16*)nxt(16777216);
    // att outputs alias the Xb buffers (Xb dead after phase-1 GEMM)
    __hip_bfloat16* At0 = Xbl;
    __hip_bfloat16* At1 = Xbr;

    dim3 tb(32, 8);
    // X: (b, c=2048, p=1024) -> (b, p, c) bf16
    transpose_cast<<<dim3(32, 64, 4), tb, 0, stream>>>(Xl, Xbl, 2048, 1024);
    transpose_cast<<<dim3(32, 64, 4), tb, 0, stream>>>(Xr, Xbr, 2048, 1024);
    // W: [K=2048][N=2048] -> [N][K] bf16
    transpose_cast<<<dim3(64, 64, 1), tb, 0, stream>>>(Wq, Wtq, 2048, 2048);
    transpose_cast<<<dim3(64, 64, 1), tb, 0, stream>>>(Wk, Wtk, 2048, 2048);
    transpose_cast<<<dim3(64, 64, 1), tb, 0, stream>>>(Wv, Wtv, 2048, 2048);
    transpose_cast<<<dim3(64, 64, 1), tb, 0, stream>>>(Wo, Wto, 2048, 2048);
    conv_rel<<<64, 256, 0, stream>>>(rel, relb);

    GArgs g1 = {};
    g1.A[0] = Xbl; g1.A[1] = Xbl; g1.A[2] = Xbl;
    g1.A[3] = Xbr; g1.A[4] = Xbr; g1.A[5] = Xbr;
    g1.B[0] = Wtq; g1.B[1] = Wtk; g1.B[2] = Wtv;
    g1.B[3] = Wtq; g1.B[4] = Wtk; g1.B[5] = Wtv;
    g1.C[0] = Ql; g1.C[1] = Kl; g1.C[2] = Vl;
    g1.C[3] = Qr; g1.C[4] = Kr; g1.C[5] = Vr;
    g1.bias[0] = bq; g1.bias[1] = bk; g1.bias[2] = bv;
    g1.bias[3] = bq; g1.bias[4] = bk; g1.bias[5] = bv;
    gemm_bt<0><<<dim3(16, 32, 6), 256, 0, stream>>>(g1, 2048, 2048, nullptr);

    // dir0: weighted_r = attn(Q_l, K_r, V_r); dir1: weighted_l = attn(Q_r, K_l, V_l)
    attn_kernel<<<dim3(32, 8, 8), 256, 0, stream>>>(Ql, Kr, Vr, Qr, Kl, Vl, relb, At0, At1);

    // phase-2: operands swapped (A=Wo^T rows=n, B=att rows=m) -> coalesced fp32 stores
    GArgs g2 = {};
    g2.A[0] = Wto; g2.A[1] = Wto;
    g2.B[0] = At0; g2.B[1] = At1;
    g2.bias[0] = bo; g2.bias[1] = bo;
    gemm_bt<1><<<dim3(32, 16, 2), 256, 0, stream>>>(g2, 2048, 2048, out);

    copy_feats<<<16384, 256, 0, stream>>>((const float4*)Xl, (const float4*)Xr, (float4*)out);
}

// Round 3
// 366.571 us; speedup vs baseline: 1.2517x; 1.2086x over previous
//
#include <hip/hip_runtime.h>
#include <hip/hip_bf16.h>

typedef __attribute__((ext_vector_type(8))) short bf16x8;
typedef __attribute__((ext_vector_type(4))) float f32x4;

#define MFMA16(a, b, c) __builtin_amdgcn_mfma_f32_16x16x32_bf16((a), (b), (c), 0, 0, 0)

typedef __attribute__((address_space(1))) const void gconst_t;
typedef __attribute__((address_space(3))) void lds_t;
__device__ __forceinline__ void gload16(const void* gp, void* lp) {
    __builtin_amdgcn_global_load_lds((gconst_t*)gp, (lds_t*)lp, 16, 0, 0);
}

#define BAR() asm volatile("s_barrier" ::: "memory")
#define VMCNT4() asm volatile("s_waitcnt vmcnt(4)" ::: "memory")
#define VMCNT0() asm volatile("s_waitcnt vmcnt(0)" ::: "memory")
#define PRIO1() __builtin_amdgcn_s_setprio(1)
#define PRIO0() __builtin_amdgcn_s_setprio(0)

// ---------------------------------------------------------------------------
// Transpose + cast fp32 -> bf16:  in [R][C] (per z) -> out [C][R]
// ---------------------------------------------------------------------------
__global__ void transpose_cast(const float* __restrict__ in, __hip_bfloat16* __restrict__ out,
                               int R, int Ccols) {
    __shared__ float tile[32][33];
    int r0 = blockIdx.y * 32, c0 = blockIdx.x * 32;
    size_t zoff = (size_t)blockIdx.z * R * Ccols;
    const float* ib = in + zoff;
    __hip_bfloat16* ob = out + zoff;
    int tx = threadIdx.x, ty = threadIdx.y;
#pragma unroll
    for (int i = ty; i < 32; i += 8)
        tile[i][tx] = ib[(size_t)(r0 + i) * Ccols + c0 + tx];
    __syncthreads();
#pragma unroll
    for (int i = ty; i < 32; i += 8)
        ob[(size_t)(c0 + i) * R + r0 + tx] = __float2bfloat16(tile[tx][i]);
}

// rel_emb (63x256 fp32) -> bf16 padded to 64 rows (row 63 = 0)
__global__ void conv_rel(const float* __restrict__ rel, __hip_bfloat16* __restrict__ relb) {
    int i = blockIdx.x * 256 + threadIdx.x;  // 64*256 = 16384
    if (i < 64 * 256) {
        int r = i >> 8;
        relb[i] = __float2bfloat16(r < 63 ? rel[i] : 0.f);
    }
}

// ---------------------------------------------------------------------------
// 256x256-tile, BK=64, 8-wave (2x4), 8-phase counted-vmcnt GEMM (m201 template).
// C[z] = A[z] (rows=M) * B[z]^T (B stored [rowsB][K]) + bias.
// LDS 128KB: buf{0,1} x {A,B} x half{0,1}(128 rows x 64 K bf16 = 16KB).
// XOR swizzle ((row&7)<<4) applied on ds_read; inverse pre-applied to the
// global source of global_load_lds (linear LDS dest — rule #21).
// Schedule (iter i, tiles t=2i in buf0, t+1 in buf1; stages 1 half-tile/phase):
//   P1 rd A-lo,B-lo(b0)  st A1(t+1)->b1   mfma lo x lo
//   P2 rd B-hi(b0)       st B1(t+1)->b1   mfma lo x hi
//   P3 rd A-hi(b0)       st B0(t+2)->b0   mfma hi x hi
//   P4 (reuse)           st A0(t+2)->b0   mfma hi x lo   vmcnt(4)
//   P5..P8 same on buf1 with stages A1(t+2),B1(t+2)->b0; B0(t+3),A0(t+3)->b1; vmcnt(4)
// Every region is staged >=1 phase after its last read (cross-wave safe via the
// barrier at the end of the reading phase); tail re-stages identical data.
// ---------------------------------------------------------------------------
struct GArgs {
    const __hip_bfloat16* A[6];
    const __hip_bfloat16* B[6];
    void* C[6];
    const float* bias[6];
};

template <int MODE>
__global__ __launch_bounds__(512, 2) void gemm8p(GArgs ga, int N, int K,
                                                 float* __restrict__ dout) {
    __shared__ __align__(16) char smem[131072];

    // XCD-aware chunked swizzle (nwg % 8 == 0 for all our launches)
    const int gx = gridDim.x, gy = gridDim.y;
    int lid = blockIdx.x + gx * (blockIdx.y + gy * blockIdx.z);
    const int nwg = gx * gy * gridDim.z;
    int swz = (lid & 7) * (nwg >> 3) + (lid >> 3);
    const int z = swz / (gx * gy);
    int rem = swz - z * (gx * gy);
    const int by = rem / gx;
    const int bx = rem - by * gx;

    const __hip_bfloat16* __restrict__ A = ga.A[z];
    const __hip_bfloat16* __restrict__ B = ga.B[z];
    const float* __restrict__ bias = ga.bias[z];
    const int row0 = by * 256, col0 = bx * 256;

    const int tid = threadIdx.x;
    const int wave = tid >> 6, lane = tid & 63;
    const int l15 = lane & 15, lg = lane >> 4;
    const int wm = wave >> 2, wn = wave & 3;  // 2 x 4 wave grid

    // staging lane constants (source pre-swizzled, LDS dest linear)
    const int srow = tid >> 3;               // 0..63: row within 64-row chunk
    const int sch = (tid & 7) ^ (srow & 7);  // swizzled 16B chunk in row
    // ds_read lane constants
    const int xr = (l15 & 7) << 4;
    const int off0 = (lg * 16) ^ xr;       // ks=0 byte offset in 128B row
    const int off1 = (64 + lg * 16) ^ xr;  // ks=1
    const int arow = wm * 16384;                   // this wave's A half region
    const int brow = 32768 + (wn >> 1) * 16384;    // this wave's B half region
    const int bloc = (wn & 1) * 64;                // local row base in B half

    f32x4 acc[8][4] = {};
    bf16x8 a[4][2], bl[2][2], bh[2][2];

    const int NT = K >> 6;   // K-tiles (32)
    const int NI = NT >> 1;  // iterations (16)

    auto STAGE = [&](const __hip_bfloat16* base, int rowb, int T, int bufc, int isB, int h) {
#pragma unroll
        for (int L = 0; L < 2; ++L) {
            const __hip_bfloat16* g =
                base + (size_t)(rowb + h * 128 + L * 64 + srow) * K + T * 64 + sch * 8;
            gload16(g, smem + bufc * 65536 + isB * 32768 + h * 16384 + L * 8192 + wave * 1024);
        }
    };
    auto LDA = [&](int bufc, int mf, int ks) {
        return *(const bf16x8*)(smem + bufc * 65536 + arow + (mf * 16 + l15) * 128 +
                                (ks ? off1 : off0));
    };
    auto LDB = [&](int bufc, int nf, int ks) {
        return *(const bf16x8*)(smem + bufc * 65536 + brow + (bloc + nf * 16 + l15) * 128 +
                                (ks ? off1 : off0));
    };

#define READ_A(BUF, MOFF)                       \
    _Pragma("unroll") for (int mf = 0; mf < 4; ++mf) { \
        a[mf][0] = LDA(BUF, (MOFF) + mf, 0);    \
        a[mf][1] = LDA(BUF, (MOFF) + mf, 1);    \
    }
#define READ_B(BUF, NOFF, DST)                  \
    _Pragma("unroll") for (int nf = 0; nf < 2; ++nf) { \
        DST[nf][0] = LDB(BUF, (NOFF) + nf, 0);  \
        DST[nf][1] = LDB(BUF, (NOFF) + nf, 1);  \
    }
#define MFMA_QUAD(MOFF, NOFF, BR)                                                        \
    _Pragma("unroll") for (int mf = 0; mf < 4; ++mf)                                     \
    _Pragma("unroll") for (int nf = 0; nf < 2; ++nf) {                                   \
        acc[(MOFF) + mf][(NOFF) + nf] =                                                  \
            MFMA16(a[mf][0], BR[nf][0], acc[(MOFF) + mf][(NOFF) + nf]);                  \
        acc[(MOFF) + mf][(NOFF) + nf] =                                                  \
            MFMA16(a[mf][1], BR[nf][1], acc[(MOFF) + mf][(NOFF) + nf]);                  \
    }

    // prologue: tile0 complete, tile1 B0+A0 in flight
    STAGE(B, col0, 0, 0, 1, 0);
    STAGE(A, row0, 0, 0, 0, 0);
    STAGE(A, row0, 0, 0, 0, 1);
    STAGE(B, col0, 0, 0, 1, 1);
    STAGE(B, col0, 1, 1, 1, 0);
    STAGE(A, row0, 1, 1, 0, 0);
    VMCNT4();
    BAR();

#pragma unroll 1
    for (int i = 0; i < NI; ++i) {
        const int t = 2 * i;
        const int T2 = (t + 2 < NT) ? t + 2 : t;      // tail: idempotent re-stage
        const int T3 = (t + 3 < NT) ? t + 3 : t + 1;  // (same parity, same data)
        // ---- tile t (buf0) ----
        READ_A(0, 0); READ_B(0, 0, bl);
        STAGE(A, row0, t + 1, 1, 0, 1);
        BAR(); PRIO1(); MFMA_QUAD(0, 0, bl); PRIO0(); BAR();

        READ_B(0, 2, bh);
        STAGE(B, col0, t + 1, 1, 1, 1);
        BAR(); PRIO1(); MFMA_QUAD(0, 2, bh); PRIO0(); BAR();

        READ_A(0, 4);
        STAGE(B, col0, T2, 0, 1, 0);
        BAR(); PRIO1(); MFMA_QUAD(4, 2, bh); PRIO0(); BAR();

        STAGE(A, row0, T2, 0, 0, 0);
        BAR(); PRIO1(); MFMA_QUAD(4, 0, bl); PRIO0(); VMCNT4(); BAR();

        // ---- tile t+1 (buf1) ----
        READ_A(1, 0); READ_B(1, 0, bl);
        STAGE(A, row0, T2, 0, 0, 1);
        BAR(); PRIO1(); MFMA_QUAD(0, 0, bl); PRIO0(); BAR();

        READ_B(1, 2, bh);
        STAGE(B, col0, T2, 0, 1, 1);
        BAR(); PRIO1(); MFMA_QUAD(0, 2, bh); PRIO0(); BAR();

        READ_A(1, 4);
        STAGE(B, col0, T3, 1, 1, 0);
        BAR(); PRIO1(); MFMA_QUAD(4, 2, bh); PRIO0(); BAR();

        STAGE(A, row0, T3, 1, 0, 0);
        BAR(); PRIO1(); MFMA_QUAD(4, 0, bl); PRIO0(); VMCNT4(); BAR();
    }
    VMCNT0();  // drain tail stages before wave exit (LDS could be re-assigned)

    if (MODE == 0) {
        __hip_bfloat16* __restrict__ C = (__hip_bfloat16*)ga.C[z];
#pragma unroll
        for (int mf = 0; mf < 8; ++mf) {
            int m = row0 + wm * 128 + mf * 16 + lg * 4;
#pragma unroll
            for (int nf = 0; nf < 4; ++nf) {
                int n = col0 + wn * 64 + nf * 16 + l15;
                float bv = bias[n];
#pragma unroll
                for (int r = 0; r < 4; ++r)
                    C[(size_t)(m + r) * N + n] = __float2bfloat16(acc[mf][nf][r] + bv);
            }
        }
    } else {
        // rows = output channel n, cols = m = b*1024 + p (coalesced in p)
        float* __restrict__ OB = dout + (size_t)z * 16777216;
#pragma unroll
        for (int mf = 0; mf < 8; ++mf) {
            int n0 = row0 + wm * 128 + mf * 16 + lg * 4;
#pragma unroll
            for (int nf = 0; nf < 4; ++nf) {
                int m = col0 + wn * 64 + nf * 16 + l15;
                size_t base = (size_t)(m >> 10) * 4194304 + (size_t)(m & 1023);
#pragma unroll
                for (int r = 0; r < 4; ++r) {
                    int n = n0 + r;
                    OB[base + (size_t)(2048 + n) * 1024] = acc[mf][nf][r] + bias[n];
                }
            }
        }
    }
#undef READ_A
#undef READ_B
#undef MFMA_QUAD
}

// ---------------------------------------------------------------------------
// Axial attention: one block per (dir, b, head, w).  Q,K,V row-major [4096][2048] bf16.
// ---------------------------------------------------------------------------
__global__ __launch_bounds__(256, 2) void attn_kernel(
    const __hip_bfloat16* __restrict__ Qa, const __hip_bfloat16* __restrict__ Ka,
    const __hip_bfloat16* __restrict__ Va, const __hip_bfloat16* __restrict__ Qb,
    const __hip_bfloat16* __restrict__ Kb, const __hip_bfloat16* __restrict__ Vb,
    const __hip_bfloat16* __restrict__ relb, __hip_bfloat16* __restrict__ Oa,
    __hip_bfloat16* __restrict__ Ob) {
    const int w = blockIdx.x;   // 0..31
    const int nh = blockIdx.y;  // 0..7
    const int zb = blockIdx.z;  // dir*4 + b
    const int dir = zb >> 2, b = zb & 3;
    const __hip_bfloat16* __restrict__ Q = dir ? Qb : Qa;
    const __hip_bfloat16* __restrict__ K = dir ? Kb : Ka;
    const __hip_bfloat16* __restrict__ V = dir ? Vb : Va;
    __hip_bfloat16* __restrict__ O = dir ? Ob : Oa;

    __shared__ __align__(16) __hip_bfloat16 vt[256 * 40];  // V^T, stride 40
    __shared__ float ssc[32 * 32];
    __shared__ float es[32 * 64];
    __shared__ __align__(16) __hip_bfloat16 ps[32 * 32];

    const int tid = threadIdx.x;
    const int lane = tid & 63, wave = tid >> 6;
    const int l15 = lane & 15, lg = lane >> 4;
    const int mt = wave >> 1, nt = wave & 1;

    const size_t rowbase = ((size_t)b * 1024 + w) * 2048 + (size_t)nh * 256;

    // stage V transposed: vt[c][hk]
    for (int i = 0; i < 32; ++i) {
        int e = i * 256 + tid;
        int hk = e >> 8, c = e & 255;
        vt[c * 40 + hk] = V[rowbase + (size_t)hk * 65536 + c];
    }

    f32x4 sacc = {}, e0 = {}, e1 = {};
#pragma unroll
    for (int k8 = 0; k8 < 256; k8 += 32) {
        bf16x8 af = *(const bf16x8*)&Q[rowbase + (size_t)(mt * 16 + l15) * 65536 + k8 + lg * 8];
        bf16x8 bf = *(const bf16x8*)&K[rowbase + (size_t)(nt * 16 + l15) * 65536 + k8 + lg * 8];
        bf16x8 r0 = *(const bf16x8*)&relb[(size_t)(nt * 32 + l15) * 256 + k8 + lg * 8];
        bf16x8 r1 = *(const bf16x8*)&relb[(size_t)(nt * 32 + 16 + l15) * 256 + k8 + lg * 8];
        sacc = MFMA16(af, bf, sacc);
        e0 = MFMA16(af, r0, e0);
        e1 = MFMA16(af, r1, e1);
    }
#pragma unroll
    for (int r = 0; r < 4; ++r) {
        int row = mt * 16 + lg * 4 + r;
        ssc[row * 32 + nt * 16 + l15] = sacc[r];
        es[row * 64 + nt * 32 + l15] = e0[r];
        es[row * 64 + nt * 32 + 16 + l15] = e1[r];
    }
    __syncthreads();

    {
        int h = tid >> 3, sub = tid & 7;
        float v4[4];
        float mx = -1e30f;
#pragma unroll
        for (int i = 0; i < 4; ++i) {
            int k = sub * 4 + i;
            int dh = k - h; if (dh < 0) dh += 63;
            int dw = k - w; if (dw < 0) dw += 63;
            float s = (ssc[h * 32 + k] + es[h * 64 + dh] + es[h * 64 + dw]) * 0.0625f;
            v4[i] = s;
            mx = fmaxf(mx, s);
        }
        mx = fmaxf(mx, __shfl_xor(mx, 1));
        mx = fmaxf(mx, __shfl_xor(mx, 2));
        mx = fmaxf(mx, __shfl_xor(mx, 4));
        float sum = 0.f;
#pragma unroll
        for (int i = 0; i < 4; ++i) {
            v4[i] = __expf(v4[i] - mx);
            sum += v4[i];
        }
        sum += __shfl_xor(sum, 1);
        sum += __shfl_xor(sum, 2);
        sum += __shfl_xor(sum, 4);
        float inv = 1.f / sum;
#pragma unroll
        for (int i = 0; i < 4; ++i) ps[h * 32 + sub * 4 + i] = __float2bfloat16(v4[i] * inv);
    }
    __syncthreads();

    bf16x8 paf = *(const bf16x8*)&ps[(mt * 16 + l15) * 32 + lg * 8];
#pragma unroll
    for (int j = 0; j < 8; ++j) {
        int ct = nt * 8 + j;  // 0..15
        bf16x8 bv = *(const bf16x8*)&vt[(size_t)(ct * 16 + l15) * 40 + lg * 8];
        f32x4 oacc = {};
        oacc = MFMA16(paf, bv, oacc);
#pragma unroll
        for (int r = 0; r < 4; ++r) {
            int hh = mt * 16 + lg * 4 + r;
            O[rowbase + (size_t)hh * 65536 + ct * 16 + l15] = __float2bfloat16(oacc[r]);
        }
    }
}

// ---------------------------------------------------------------------------
// Copy raw features into first 2048 channels of each output tensor
// ---------------------------------------------------------------------------
__global__ void copy_feats(const float4* __restrict__ L, const float4* __restrict__ R,
                           float4* __restrict__ out) {
    int idx = blockIdx.x * 256 + threadIdx.x;  // 0 .. 2*2097152-1
    int t = idx >= 2097152;
    int f4 = t ? idx - 2097152 : idx;
    int b = f4 >> 19, rem = f4 & 524287;  // per-batch 2^19 float4
    float4 v = t ? R[f4] : L[f4];
    out[(size_t)t * 4194304 + (size_t)b * 1048576 + rem] = v;
}

// ---------------------------------------------------------------------------
extern "C" void kernel_launch(void* const* d_in, const int* in_sizes, int n_in, void* d_out,
                              int out_size, void* d_ws, size_t ws_size, hipStream_t stream) {
    const float* Xl = (const float*)d_in[0];
    const float* Xr = (const float*)d_in[1];
    const float* Wq = (const float*)d_in[2];
    const float* bq = (const float*)d_in[3];
    const float* Wk = (const float*)d_in[4];
    const float* bk = (const float*)d_in[5];
    const float* Wv = (const float*)d_in[6];
    const float* bv = (const float*)d_in[7];
    const float* Wo = (const float*)d_in[8];
    const float* bo = (const float*)d_in[9];
    const float* rel = (const float*)d_in[10];
    float* out = (float*)d_out;

    char* ws = (char*)d_ws;
    size_t off = 0;
    auto nxt = [&](size_t bytes) {
        void* p = ws + off;
        off += bytes;
        return p;
    };
    __hip_bfloat16* Xbl = (__hip_bfloat16*)nxt(16777216);
    __hip_bfloat16* Xbr = (__hip_bfloat16*)nxt(16777216);
    __hip_bfloat16* Wtq = (__hip_bfloat16*)nxt(8388608);
    __hip_bfloat16* Wtk = (__hip_bfloat16*)nxt(8388608);
    __hip_bfloat16* Wtv = (__hip_bfloat16*)nxt(8388608);
    __hip_bfloat16* Wto = (__hip_bfloat16*)nxt(8388608);
    __hip_bfloat16* relb = (__hip_bfloat16*)nxt(32768);
    __hip_bfloat16* Ql = (__hip_bfloat16*)nxt(16777216);
    __hip_bfloat16* Kl = (__hip_bfloat16*)nxt(16777216);
    __hip_bfloat16* Vl = (__hip_bfloat16*)nxt(16777216);
    __hip_bfloat16* Qr = (__hip_bfloat16*)nxt(16777216);
    __hip_bfloat16* Kr = (__hip_bfloat16*)nxt(16777216);
    __hip_bfloat16* Vr = (__hip_bfloat16*)nxt(16777216);
    // att outputs alias the Xb buffers (Xb dead after phase-1 GEMM)
    __hip_bfloat16* At0 = Xbl;
    __hip_bfloat16* At1 = Xbr;

    dim3 tb(32, 8);
    transpose_cast<<<dim3(32, 64, 4), tb, 0, stream>>>(Xl, Xbl, 2048, 1024);
    transpose_cast<<<dim3(32, 64, 4), tb, 0, stream>>>(Xr, Xbr, 2048, 1024);
    transpose_cast<<<dim3(64, 64, 1), tb, 0, stream>>>(Wq, Wtq, 2048, 2048);
    transpose_cast<<<dim3(64, 64, 1), tb, 0, stream>>>(Wk, Wtk, 2048, 2048);
    transpose_cast<<<dim3(64, 64, 1), tb, 0, stream>>>(Wv, Wtv, 2048, 2048);
    transpose_cast<<<dim3(64, 64, 1), tb, 0, stream>>>(Wo, Wto, 2048, 2048);
    conv_rel<<<64, 256, 0, stream>>>(rel, relb);

    GArgs g1 = {};
    g1.A[0] = Xbl; g1.A[1] = Xbl; g1.A[2] = Xbl;
    g1.A[3] = Xbr; g1.A[4] = Xbr; g1.A[5] = Xbr;
    g1.B[0] = Wtq; g1.B[1] = Wtk; g1.B[2] = Wtv;
    g1.B[3] = Wtq; g1.B[4] = Wtk; g1.B[5] = Wtv;
    g1.C[0] = Ql; g1.C[1] = Kl; g1.C[2] = Vl;
    g1.C[3] = Qr; g1.C[4] = Kr; g1.C[5] = Vr;
    g1.bias[0] = bq; g1.bias[1] = bk; g1.bias[2] = bv;
    g1.bias[3] = bq; g1.bias[4] = bk; g1.bias[5] = bv;
    // M=4096 (16 m-tiles), N=2048 (8 n-tiles), z=6 -> 768 blocks
    gemm8p<0><<<dim3(8, 16, 6), 512, 0, stream>>>(g1, 2048, 2048, nullptr);

    // dir0: weighted_r = attn(Q_l, K_r, V_r); dir1: weighted_l = attn(Q_r, K_l, V_l)
    attn_kernel<<<dim3(32, 8, 8), 256, 0, stream>>>(Ql, Kr, Vr, Qr, Kl, Vl, relb, At0, At1);

    // phase-2: operands swapped (A=Wo^T rows=n 2048, B=att rows=m 4096)
    GArgs g2 = {};
    g2.A[0] = Wto; g2.A[1] = Wto;
    g2.B[0] = At0; g2.B[1] = At1;
    g2.bias[0] = bo; g2.bias[1] = bo;
    gemm8p<1><<<dim3(16, 8, 2), 512, 0, stream>>>(g2, 2048, 2048, out);

    copy_feats<<<16384, 256, 0, stream>>>((const float4*)Xl, (const float4*)Xr, (float4*)out);
}

// Round 4
// 353.841 us; speedup vs baseline: 1.2967x; 1.0360x over previous
//
#include <hip/hip_runtime.h>
#include <hip/hip_bf16.h>

typedef __attribute__((ext_vector_type(8))) short bf16x8;
typedef __attribute__((ext_vector_type(4))) float f32x4;

#define MFMA16(a, b, c) __builtin_amdgcn_mfma_f32_16x16x32_bf16((a), (b), (c), 0, 0, 0)

typedef __attribute__((address_space(1))) const void gconst_t;
typedef __attribute__((address_space(3))) void lds_t;
__device__ __forceinline__ void gload16(const void* gp, void* lp) {
    __builtin_amdgcn_global_load_lds((gconst_t*)gp, (lds_t*)lp, 16, 0, 0);
}

#define BAR() asm volatile("s_barrier" ::: "memory")
#define VMCNT4() asm volatile("s_waitcnt vmcnt(4)" ::: "memory")
#define VMCNT0() asm volatile("s_waitcnt vmcnt(0)" ::: "memory")
#define PRIO1() __builtin_amdgcn_s_setprio(1)
#define PRIO0() __builtin_amdgcn_s_setprio(0)

// ---------------------------------------------------------------------------
// Transpose + cast fp32 -> bf16:  in [R][C] (per z) -> out [C][R].
// If copy_out != nullptr (X tensors: R=2048, C=1024), also write the raw fp32
// tile to copy_out[z*4194304 + r*1024 + c] (the concat output's first 2048 ch).
// ---------------------------------------------------------------------------
__global__ void transpose_cast(const float* __restrict__ in, __hip_bfloat16* __restrict__ out,
                               int R, int Ccols, float* __restrict__ copy_out) {
    __shared__ float tile[32][33];
    int r0 = blockIdx.y * 32, c0 = blockIdx.x * 32;
    size_t zoff = (size_t)blockIdx.z * R * Ccols;
    const float* ib = in + zoff;
    __hip_bfloat16* ob = out + zoff;
    int tx = threadIdx.x, ty = threadIdx.y;
    if (copy_out) {
        float* cb = copy_out + (size_t)blockIdx.z * 4194304;
#pragma unroll
        for (int i = ty; i < 32; i += 8) {
            float v = ib[(size_t)(r0 + i) * Ccols + c0 + tx];
            tile[i][tx] = v;
            cb[(size_t)(r0 + i) * Ccols + c0 + tx] = v;
        }
    } else {
#pragma unroll
        for (int i = ty; i < 32; i += 8)
            tile[i][tx] = ib[(size_t)(r0 + i) * Ccols + c0 + tx];
    }
    __syncthreads();
#pragma unroll
    for (int i = ty; i < 32; i += 8)
        ob[(size_t)(c0 + i) * R + r0 + tx] = __float2bfloat16(tile[tx][i]);
}

// rel_emb (63x256 fp32) -> bf16 padded to 64 rows (row 63 = 0)
__global__ void conv_rel(const float* __restrict__ rel, __hip_bfloat16* __restrict__ relb) {
    int i = blockIdx.x * 256 + threadIdx.x;  // 64*256 = 16384
    if (i < 64 * 256) {
        int r = i >> 8;
        relb[i] = __float2bfloat16(r < 63 ? rel[i] : 0.f);
    }
}

// ---------------------------------------------------------------------------
// 256x256-tile, BK=64, 8-wave (2x4), 8-phase counted-vmcnt GEMM.
// SINGLE barrier per phase: [reads | stage-issue | vmcnt-gate] BAR [MFMA].
// MFMA of phase p overlaps ds_reads of phase p+1 (different pipes, wave skew
// allowed). Race safety: reads/stages keep the same position relative to the
// surviving barrier as in the 2-barrier version; vmcnt(4) gates at P4/P8
// drain exactly the buffer read next (per-wave count + barrier = all-wave
// visibility).  Tail iterations re-stage identical data (idempotent).
// ---------------------------------------------------------------------------
struct GArgs {
    const __hip_bfloat16* A[6];
    const __hip_bfloat16* B[6];
    void* C[6];
    const float* bias[6];
};

template <int MODE>
__global__ __launch_bounds__(512, 2) void gemm8p(GArgs ga, int N, int K,
                                                 float* __restrict__ dout) {
    __shared__ __align__(16) char smem[131072];

    // XCD-aware chunked swizzle (nwg % 8 == 0 for all our launches)
    const int gx = gridDim.x, gy = gridDim.y;
    int lid = blockIdx.x + gx * (blockIdx.y + gy * blockIdx.z);
    const int nwg = gx * gy * gridDim.z;
    int swz = (lid & 7) * (nwg >> 3) + (lid >> 3);
    const int z = swz / (gx * gy);
    int rem = swz - z * (gx * gy);
    const int by = rem / gx;
    const int bx = rem - by * gx;

    const __hip_bfloat16* __restrict__ A = ga.A[z];
    const __hip_bfloat16* __restrict__ B = ga.B[z];
    const float* __restrict__ bias = ga.bias[z];
    const int row0 = by * 256, col0 = bx * 256;

    const int tid = threadIdx.x;
    const int wave = tid >> 6, lane = tid & 63;
    const int l15 = lane & 15, lg = lane >> 4;
    const int wm = wave >> 2, wn = wave & 3;  // 2 x 4 wave grid

    // staging lane constants (source pre-swizzled, LDS dest linear)
    const int srow = tid >> 3;               // 0..63: row within 64-row chunk
    const int sch = (tid & 7) ^ (srow & 7);  // swizzled 16B chunk in row
    // ds_read lane constants
    const int xr = (l15 & 7) << 4;
    const int off0 = (lg * 16) ^ xr;       // ks=0 byte offset in 128B row
    const int off1 = (64 + lg * 16) ^ xr;  // ks=1
    const int arow = wm * 16384;                 // this wave's A half region
    const int brow = 32768 + (wn >> 1) * 16384;  // this wave's B half region
    const int bloc = (wn & 1) * 64;              // local row base in B half

    f32x4 acc[8][4] = {};
    bf16x8 a[4][2], bl[2][2], bh[2][2];

    const int NT = K >> 6;   // K-tiles (32)
    const int NI = NT >> 1;  // iterations (16)

    auto STAGE = [&](const __hip_bfloat16* base, int rowb, int T, int bufc, int isB, int h) {
#pragma unroll
        for (int L = 0; L < 2; ++L) {
            const __hip_bfloat16* g =
                base + (size_t)(rowb + h * 128 + L * 64 + srow) * K + T * 64 + sch * 8;
            gload16(g, smem + bufc * 65536 + isB * 32768 + h * 16384 + L * 8192 + wave * 1024);
        }
    };
    auto LDA = [&](int bufc, int mf, int ks) {
        return *(const bf16x8*)(smem + bufc * 65536 + arow + (mf * 16 + l15) * 128 +
                                (ks ? off1 : off0));
    };
    auto LDB = [&](int bufc, int nf, int ks) {
        return *(const bf16x8*)(smem + bufc * 65536 + brow + (bloc + nf * 16 + l15) * 128 +
                                (ks ? off1 : off0));
    };

#define READ_A(BUF, MOFF)                       \
    _Pragma("unroll") for (int mf = 0; mf < 4; ++mf) { \
        a[mf][0] = LDA(BUF, (MOFF) + mf, 0);    \
        a[mf][1] = LDA(BUF, (MOFF) + mf, 1);    \
    }
#define READ_B(BUF, NOFF, DST)                  \
    _Pragma("unroll") for (int nf = 0; nf < 2; ++nf) { \
        DST[nf][0] = LDB(BUF, (NOFF) + nf, 0);  \
        DST[nf][1] = LDB(BUF, (NOFF) + nf, 1);  \
    }
#define MFMA_QUAD(MOFF, NOFF, BR)                                                        \
    _Pragma("unroll") for (int mf = 0; mf < 4; ++mf)                                     \
    _Pragma("unroll") for (int nf = 0; nf < 2; ++nf) {                                   \
        acc[(MOFF) + mf][(NOFF) + nf] =                                                  \
            MFMA16(a[mf][0], BR[nf][0], acc[(MOFF) + mf][(NOFF) + nf]);                  \
        acc[(MOFF) + mf][(NOFF) + nf] =                                                  \
            MFMA16(a[mf][1], BR[nf][1], acc[(MOFF) + mf][(NOFF) + nf]);                  \
    }

    // prologue: tile0 complete, tile1 B0+A0 in flight
    STAGE(B, col0, 0, 0, 1, 0);
    STAGE(A, row0, 0, 0, 0, 0);
    STAGE(A, row0, 0, 0, 0, 1);
    STAGE(B, col0, 0, 0, 1, 1);
    STAGE(B, col0, 1, 1, 1, 0);
    STAGE(A, row0, 1, 1, 0, 0);
    VMCNT4();
    BAR();

#pragma unroll 1
    for (int i = 0; i < NI; ++i) {
        const int t = 2 * i;
        const int T2 = (t + 2 < NT) ? t + 2 : t;      // tail: idempotent re-stage
        const int T3 = (t + 3 < NT) ? t + 3 : t + 1;  // (same parity, same data)
        // ---- tile t (buf0) ----
        READ_A(0, 0); READ_B(0, 0, bl);
        STAGE(A, row0, t + 1, 1, 0, 1);
        BAR(); PRIO1(); MFMA_QUAD(0, 0, bl); PRIO0();

        READ_B(0, 2, bh);
        STAGE(B, col0, t + 1, 1, 1, 1);
        BAR(); PRIO1(); MFMA_QUAD(0, 2, bh); PRIO0();

        READ_A(0, 4);
        STAGE(B, col0, T2, 0, 1, 0);
        BAR(); PRIO1(); MFMA_QUAD(4, 2, bh); PRIO0();

        STAGE(A, row0, T2, 0, 0, 0);
        VMCNT4();
        BAR(); PRIO1(); MFMA_QUAD(4, 0, bl); PRIO0();

        // ---- tile t+1 (buf1) ----
        READ_A(1, 0); READ_B(1, 0, bl);
        STAGE(A, row0, T2, 0, 0, 1);
        BAR(); PRIO1(); MFMA_QUAD(0, 0, bl); PRIO0();

        READ_B(1, 2, bh);
        STAGE(B, col0, T2, 0, 1, 1);
        BAR(); PRIO1(); MFMA_QUAD(0, 2, bh); PRIO0();

        READ_A(1, 4);
        STAGE(B, col0, T3, 1, 1, 0);
        BAR(); PRIO1(); MFMA_QUAD(4, 2, bh); PRIO0();

        STAGE(A, row0, T3, 1, 0, 0);
        VMCNT4();
        BAR(); PRIO1(); MFMA_QUAD(4, 0, bl); PRIO0();
    }
    VMCNT0();  // drain tail stages before wave exit

    if (MODE == 0) {
        __hip_bfloat16* __restrict__ C = (__hip_bfloat16*)ga.C[z];
#pragma unroll
        for (int mf = 0; mf < 8; ++mf) {
            int m = row0 + wm * 128 + mf * 16 + lg * 4;
#pragma unroll
            for (int nf = 0; nf < 4; ++nf) {
                int n = col0 + wn * 64 + nf * 16 + l15;
                float bv = bias[n];
#pragma unroll
                for (int r = 0; r < 4; ++r)
                    C[(size_t)(m + r) * N + n] = __float2bfloat16(acc[mf][nf][r] + bv);
            }
        }
    } else {
        // rows = output channel n, cols = m = b*1024 + p (coalesced in p)
        float* __restrict__ OB = dout + (size_t)z * 16777216;
#pragma unroll
        for (int mf = 0; mf < 8; ++mf) {
            int n0 = row0 + wm * 128 + mf * 16 + lg * 4;
#pragma unroll
            for (int nf = 0; nf < 4; ++nf) {
                int m = col0 + wn * 64 + nf * 16 + l15;
                size_t base = (size_t)(m >> 10) * 4194304 + (size_t)(m & 1023);
#pragma unroll
                for (int r = 0; r < 4; ++r) {
                    int n = n0 + r;
                    OB[base + (size_t)(2048 + n) * 1024] = acc[mf][nf][r] + bias[n];
                }
            }
        }
    }
#undef READ_A
#undef READ_B
#undef MFMA_QUAD
}

// ---------------------------------------------------------------------------
// Axial attention: one block per (dir, b, head, w).  Q,K,V row-major [4096][2048] bf16.
// ---------------------------------------------------------------------------
__global__ __launch_bounds__(256, 2) void attn_kernel(
    const __hip_bfloat16* __restrict__ Qa, const __hip_bfloat16* __restrict__ Ka,
    const __hip_bfloat16* __restrict__ Va, const __hip_bfloat16* __restrict__ Qb,
    const __hip_bfloat16* __restrict__ Kb, const __hip_bfloat16* __restrict__ Vb,
    const __hip_bfloat16* __restrict__ relb, __hip_bfloat16* __restrict__ Oa,
    __hip_bfloat16* __restrict__ Ob) {
    const int w = blockIdx.x;   // 0..31
    const int nh = blockIdx.y;  // 0..7
    const int zb = blockIdx.z;  // dir*4 + b
    const int dir = zb >> 2, b = zb & 3;
    const __hip_bfloat16* __restrict__ Q = dir ? Qb : Qa;
    const __hip_bfloat16* __restrict__ K = dir ? Kb : Ka;
    const __hip_bfloat16* __restrict__ V = dir ? Vb : Va;
    __hip_bfloat16* __restrict__ O = dir ? Ob : Oa;

    __shared__ __align__(16) __hip_bfloat16 vt[256 * 40];  // V^T, stride 40
    __shared__ float ssc[32 * 32];
    __shared__ float es[32 * 64];
    __shared__ __align__(16) __hip_bfloat16 ps[32 * 32];

    const int tid = threadIdx.x;
    const int lane = tid & 63, wave = tid >> 6;
    const int l15 = lane & 15, lg = lane >> 4;
    const int mt = wave >> 1, nt = wave & 1;

    const size_t rowbase = ((size_t)b * 1024 + w) * 2048 + (size_t)nh * 256;

    // stage V transposed: vt[c][hk]
    for (int i = 0; i < 32; ++i) {
        int e = i * 256 + tid;
        int hk = e >> 8, c = e & 255;
        vt[c * 40 + hk] = V[rowbase + (size_t)hk * 65536 + c];
    }

    f32x4 sacc = {}, e0 = {}, e1 = {};
#pragma unroll
    for (int k8 = 0; k8 < 256; k8 += 32) {
        bf16x8 af = *(const bf16x8*)&Q[rowbase + (size_t)(mt * 16 + l15) * 65536 + k8 + lg * 8];
        bf16x8 bf = *(const bf16x8*)&K[rowbase + (size_t)(nt * 16 + l15) * 65536 + k8 + lg * 8];
        bf16x8 r0 = *(const bf16x8*)&relb[(size_t)(nt * 32 + l15) * 256 + k8 + lg * 8];
        bf16x8 r1 = *(const bf16x8*)&relb[(size_t)(nt * 32 + 16 + l15) * 256 + k8 + lg * 8];
        sacc = MFMA16(af, bf, sacc);
        e0 = MFMA16(af, r0, e0);
        e1 = MFMA16(af, r1, e1);
    }
#pragma unroll
    for (int r = 0; r < 4; ++r) {
        int row = mt * 16 + lg * 4 + r;
        ssc[row * 32 + nt * 16 + l15] = sacc[r];
        es[row * 64 + nt * 32 + l15] = e0[r];
        es[row * 64 + nt * 32 + 16 + l15] = e1[r];
    }
    __syncthreads();

    {
        int h = tid >> 3, sub = tid & 7;
        float v4[4];
        float mx = -1e30f;
#pragma unroll
        for (int i = 0; i < 4; ++i) {
            int k = sub * 4 + i;
            int dh = k - h; if (dh < 0) dh += 63;
            int dw = k - w; if (dw < 0) dw += 63;
            float s = (ssc[h * 32 + k] + es[h * 64 + dh] + es[h * 64 + dw]) * 0.0625f;
            v4[i] = s;
            mx = fmaxf(mx, s);
        }
        mx = fmaxf(mx, __shfl_xor(mx, 1));
        mx = fmaxf(mx, __shfl_xor(mx, 2));
        mx = fmaxf(mx, __shfl_xor(mx, 4));
        float sum = 0.f;
#pragma unroll
        for (int i = 0; i < 4; ++i) {
            v4[i] = __expf(v4[i] - mx);
            sum += v4[i];
        }
        sum += __shfl_xor(sum, 1);
        sum += __shfl_xor(sum, 2);
        sum += __shfl_xor(sum, 4);
        float inv = 1.f / sum;
#pragma unroll
        for (int i = 0; i < 4; ++i) ps[h * 32 + sub * 4 + i] = __float2bfloat16(v4[i] * inv);
    }
    __syncthreads();

    bf16x8 paf = *(const bf16x8*)&ps[(mt * 16 + l15) * 32 + lg * 8];
#pragma unroll
    for (int j = 0; j < 8; ++j) {
        int ct = nt * 8 + j;  // 0..15
        bf16x8 bv = *(const bf16x8*)&vt[(size_t)(ct * 16 + l15) * 40 + lg * 8];
        f32x4 oacc = {};
        oacc = MFMA16(paf, bv, oacc);
#pragma unroll
        for (int r = 0; r < 4; ++r) {
            int hh = mt * 16 + lg * 4 + r;
            O[rowbase + (size_t)hh * 65536 + ct * 16 + l15] = __float2bfloat16(oacc[r]);
        }
    }
}

// ---------------------------------------------------------------------------
extern "C" void kernel_launch(void* const* d_in, const int* in_sizes, int n_in, void* d_out,
                              int out_size, void* d_ws, size_t ws_size, hipStream_t stream) {
    const float* Xl = (const float*)d_in[0];
    const float* Xr = (const float*)d_in[1];
    const float* Wq = (const float*)d_in[2];
    const float* bq = (const float*)d_in[3];
    const float* Wk = (const float*)d_in[4];
    const float* bk = (const float*)d_in[5];
    const float* Wv = (const float*)d_in[6];
    const float* bv = (const float*)d_in[7];
    const float* Wo = (const float*)d_in[8];
    const float* bo = (const float*)d_in[9];
    const float* rel = (const float*)d_in[10];
    float* out = (float*)d_out;

    char* ws = (char*)d_ws;
    size_t off = 0;
    auto nxt = [&](size_t bytes) {
        void* p = ws + off;
        off += bytes;
        return p;
    };
    __hip_bfloat16* Xbl = (__hip_bfloat16*)nxt(16777216);
    __hip_bfloat16* Xbr = (__hip_bfloat16*)nxt(16777216);
    __hip_bfloat16* Wtq = (__hip_bfloat16*)nxt(8388608);
    __hip_bfloat16* Wtk = (__hip_bfloat16*)nxt(8388608);
    __hip_bfloat16* Wtv = (__hip_bfloat16*)nxt(8388608);
    __hip_bfloat16* Wto = (__hip_bfloat16*)nxt(8388608);
    __hip_bfloat16* relb = (__hip_bfloat16*)nxt(32768);
    __hip_bfloat16* Ql = (__hip_bfloat16*)nxt(16777216);
    __hip_bfloat16* Kl = (__hip_bfloat16*)nxt(16777216);
    __hip_bfloat16* Vl = (__hip_bfloat16*)nxt(16777216);
    __hip_bfloat16* Qr = (__hip_bfloat16*)nxt(16777216);
    __hip_bfloat16* Kr = (__hip_bfloat16*)nxt(16777216);
    __hip_bfloat16* Vr = (__hip_bfloat16*)nxt(16777216);
    // att outputs alias the Xb buffers (Xb dead after phase-1 GEMM)
    __hip_bfloat16* At0 = Xbl;
    __hip_bfloat16* At1 = Xbr;

    dim3 tb(32, 8);
    // X transposes also emit the raw-feature fp32 copy into the concat output
    transpose_cast<<<dim3(32, 64, 4), tb, 0, stream>>>(Xl, Xbl, 2048, 1024, out);
    transpose_cast<<<dim3(32, 64, 4), tb, 0, stream>>>(Xr, Xbr, 2048, 1024, out + 16777216);
    transpose_cast<<<dim3(64, 64, 1), tb, 0, stream>>>(Wq, Wtq, 2048, 2048, nullptr);
    transpose_cast<<<dim3(64, 64, 1), tb, 0, stream>>>(Wk, Wtk, 2048, 2048, nullptr);
    transpose_cast<<<dim3(64, 64, 1), tb, 0, stream>>>(Wv, Wtv, 2048, 2048, nullptr);
    transpose_cast<<<dim3(64, 64, 1), tb, 0, stream>>>(Wo, Wto, 2048, 2048, nullptr);
    conv_rel<<<64, 256, 0, stream>>>(rel, relb);

    GArgs g1 = {};
    g1.A[0] = Xbl; g1.A[1] = Xbl; g1.A[2] = Xbl;
    g1.A[3] = Xbr; g1.A[4] = Xbr; g1.A[5] = Xbr;
    g1.B[0] = Wtq; g1.B[1] = Wtk; g1.B[2] = Wtv;
    g1.B[3] = Wtq; g1.B[4] = Wtk; g1.B[5] = Wtv;
    g1.C[0] = Ql; g1.C[1] = Kl; g1.C[2] = Vl;
    g1.C[3] = Qr; g1.C[4] = Kr; g1.C[5] = Vr;
    g1.bias[0] = bq; g1.bias[1] = bk; g1.bias[2] = bv;
    g1.bias[3] = bq; g1.bias[4] = bk; g1.bias[5] = bv;
    // M=4096 (16 m-tiles), N=2048 (8 n-tiles), z=6 -> 768 blocks
    gemm8p<0><<<dim3(8, 16, 6), 512, 0, stream>>>(g1, 2048, 2048, nullptr);

    // dir0: weighted_r = attn(Q_l, K_r, V_r); dir1: weighted_l = attn(Q_r, K_l, V_l)
    attn_kernel<<<dim3(32, 8, 8), 256, 0, stream>>>(Ql, Kr, Vr, Qr, Kl, Vl, relb, At0, At1);

    // phase-2: operands swapped (A=Wo^T rows=n 2048, B=att rows=m 4096)
    GArgs g2 = {};
    g2.A[0] = Wto; g2.A[1] = Wto;
    g2.B[0] = At0; g2.B[1] = At1;
    g2.bias[0] = bo; g2.bias[1] = bo;
    gemm8p<1><<<dim3(16, 8, 2), 512, 0, stream>>>(g2, 2048, 2048, out);
}